// Round 3
// baseline (425.318 us; speedup 1.0000x reference)
//
#include <hip/hip_runtime.h>
#include <hip/hip_bf16.h>

typedef __bf16 bf16x8 __attribute__((ext_vector_type(8)));
typedef float f32x4 __attribute__((ext_vector_type(4)));

// Problem constants
#define S_LEN 2048
#define D_DIM 128
#define BH 32            // B*H
#define BM 128           // q rows per block
#define BN 64            // keys per k-tile
#define NT (S_LEN / BN)  // 32 k-tiles
#define NWAVE 8          // 512 threads; each wave owns 16 q rows
// 1/sqrt(128) * log2(e): scores land pre-multiplied, exp() becomes raw v_exp_f32 (exp2)
#define QSCALE (0.08838834764831845f * 1.4426950408889634f)

__global__ __launch_bounds__(512, 4)  // cap VGPR<=128: 2 blocks/CU, 16 waves
void fa_fwd_kernel(const float* __restrict__ Qg, const float* __restrict__ Kg,
                   const float* __restrict__ Vg, float* __restrict__ Og) {
    // K: [k][d] (+8 pad). V: transposed [d][k], col-block swizzle
    //   element(k,d) at col ((k>>3) ^ ((d>>3)&7))*8 + (k&7): 2-way write banks, 16B reads.
    // P: per-wave scratch (wave-local: no barrier needed around its round-trip).
    __shared__ __bf16 Klds[BN][D_DIM + 8];        // 17408 B
    __shared__ __bf16 Vlds[D_DIM][BN + 8];        // 18432 B
    __shared__ __bf16 Plds[NWAVE][16][BN + 8];    // 18432 B   (total 54272)

    const int bh   = blockIdx.x & (BH - 1);   // head-minor: same head -> same XCD
    const int qt   = blockIdx.x >> 5;
    const int tid  = threadIdx.x;
    const int wave = tid >> 6;
    const int lane = tid & 63;
    const int quad = lane >> 4;
    const int m16  = lane & 15;

    const float* Qh = Qg + bh * (S_LEN * D_DIM);
    const float* Kh = Kg + bh * (S_LEN * D_DIM);
    const float* Vh = Vg + bh * (S_LEN * D_DIM);
    float*       Oh = Og + bh * (S_LEN * D_DIM);

    const int qrow_base = qt * BM + wave * 16;

    // ---- Q fragments (A-layout: A[m=lane&15][k=quad*8+j]), scale*log2e folded ----
    bf16x8 qf[4];
#pragma unroll
    for (int ks = 0; ks < 4; ++ks) {
        const float* qp = Qh + (qrow_base + m16) * D_DIM + ks * 32 + quad * 8;
        const float4 a = *(const float4*)(qp);
        const float4 b = *(const float4*)(qp + 4);
        bf16x8 f;
        f[0] = (__bf16)(a.x * QSCALE); f[1] = (__bf16)(a.y * QSCALE);
        f[2] = (__bf16)(a.z * QSCALE); f[3] = (__bf16)(a.w * QSCALE);
        f[4] = (__bf16)(b.x * QSCALE); f[5] = (__bf16)(b.y * QSCALE);
        f[6] = (__bf16)(b.z * QSCALE); f[7] = (__bf16)(b.w * QSCALE);
        qf[ks] = f;
    }

    f32x4 o_acc[8];
#pragma unroll
    for (int nt = 0; nt < 8; ++nt) {
        o_acc[nt][0] = 0.f; o_acc[nt][1] = 0.f; o_acc[nt][2] = 0.f; o_acc[nt][3] = 0.f;
    }
    float m_st[4], l_st[4];
#pragma unroll
    for (int r = 0; r < 4; ++r) { m_st[r] = -1e30f; l_st[r] = 0.f; }

    // ---- prefetch registers (single set; cvt/ds_write consume at issue) ----
    const int c4 = tid & 31, rp = tid >> 5;   // V-staging coords
    float4 kr[2][2], vr[2][2];

    auto prefetch = [&](int kt) {
        const float* kg = Kh + kt * BN * D_DIM;
#pragma unroll
        for (int i = 0; i < 2; ++i) {
            const int idx = tid + i * 512;          // 0..1023 chunks of 8 floats
            const int r = idx >> 4, c8 = idx & 15;
            kr[i][0] = *(const float4*)(kg + r * D_DIM + c8 * 8);
            kr[i][1] = *(const float4*)(kg + r * D_DIM + c8 * 8 + 4);
        }
        const float* vg = Vh + kt * BN * D_DIM;
#pragma unroll
        for (int i = 0; i < 2; ++i) {
            const int r = (rp + i * 16) * 2;        // even row 0..62
            vr[i][0] = *(const float4*)(vg + r * D_DIM + c4 * 4);
            vr[i][1] = *(const float4*)(vg + (r + 1) * D_DIM + c4 * 4);
        }
    };

    prefetch(0);

    for (int kt = 0; kt < NT; ++kt) {
        __syncthreads();  // all waves done reading LDS tiles of kt-1

        // ---- convert prefetched regs -> LDS ----
#pragma unroll
        for (int i = 0; i < 2; ++i) {
            const int idx = tid + i * 512;
            const int r = idx >> 4, c8 = idx & 15;
            const float4 a = kr[i][0], b = kr[i][1];
            bf16x8 w;
            w[0] = (__bf16)a.x; w[1] = (__bf16)a.y; w[2] = (__bf16)a.z; w[3] = (__bf16)a.w;
            w[4] = (__bf16)b.x; w[5] = (__bf16)b.y; w[6] = (__bf16)b.z; w[7] = (__bf16)b.w;
            *(bf16x8*)&Klds[r][c8 * 8] = w;
        }
#pragma unroll
        for (int i = 0; i < 2; ++i) {
            const int r = (rp + i * 16) * 2;
            const float* p0 = reinterpret_cast<const float*>(&vr[i][0]);
            const float* p1 = reinterpret_cast<const float*>(&vr[i][1]);
            const int kb = r >> 3, jj = r & 7;
#pragma unroll
            for (int j = 0; j < 4; ++j) {
                const int d = c4 * 4 + j;
                union { __bf16 h[2]; unsigned int u; } pk;
                pk.h[0] = (__bf16)p0[j]; pk.h[1] = (__bf16)p1[j];
                *(unsigned int*)&Vlds[d][((kb ^ ((d >> 3) & 7)) << 3) + jj] = pk.u;
            }
        }

        // ---- issue next tile's global loads; latency hides under compute ----
        if (kt + 1 < NT) prefetch(kt + 1);

        __syncthreads();  // LDS tiles ready

        // ---- S = (Q*scale*log2e) K^T ----
        f32x4 sacc[4];
#pragma unroll
        for (int nt = 0; nt < 4; ++nt) {
            sacc[nt][0] = 0.f; sacc[nt][1] = 0.f; sacc[nt][2] = 0.f; sacc[nt][3] = 0.f;
        }
#pragma unroll
        for (int ks = 0; ks < 4; ++ks)
#pragma unroll
            for (int nt = 0; nt < 4; ++nt) {
                const bf16x8 kf = *(const bf16x8*)&Klds[nt * 16 + m16][ks * 32 + quad * 8];
                sacc[nt] = __builtin_amdgcn_mfma_f32_16x16x32_bf16(qf[ks], kf, sacc[nt], 0, 0, 0);
            }

        // ---- online softmax, exp2 domain (C-rows: quad*4+r) ----
        {
            float mx[4];
#pragma unroll
            for (int r = 0; r < 4; ++r)
                mx[r] = fmaxf(fmaxf(sacc[0][r], sacc[1][r]), fmaxf(sacc[2][r], sacc[3][r]));
#pragma unroll
            for (int xm = 1; xm <= 8; xm <<= 1)
#pragma unroll
                for (int r = 0; r < 4; ++r)
                    mx[r] = fmaxf(mx[r], __shfl_xor(mx[r], xm, 64));
            float alpha[4], rs[4];
#pragma unroll
            for (int r = 0; r < 4; ++r) {
                const float mnew = fmaxf(m_st[r], mx[r]);
                alpha[r] = __builtin_amdgcn_exp2f(m_st[r] - mnew);
                m_st[r] = mnew;
                rs[r] = 0.f;
            }
#pragma unroll
            for (int nt = 0; nt < 4; ++nt) {
#pragma unroll
                for (int r = 0; r < 4; ++r) {
                    const float p = __builtin_amdgcn_exp2f(sacc[nt][r] - m_st[r]);
                    rs[r] += p;
                    Plds[wave][quad * 4 + r][nt * 16 + m16] = (__bf16)p;
                }
            }
#pragma unroll
            for (int xm = 1; xm <= 8; xm <<= 1)
#pragma unroll
                for (int r = 0; r < 4; ++r)
                    rs[r] += __shfl_xor(rs[r], xm, 64);
#pragma unroll
            for (int r = 0; r < 4; ++r)
                l_st[r] = l_st[r] * alpha[r] + rs[r];
#pragma unroll
            for (int nt = 0; nt < 8; ++nt)
#pragma unroll
                for (int r = 0; r < 4; ++r)
                    o_acc[nt][r] *= alpha[r];
        }
        // NO barrier: Plds[wave] is wave-local; DS pipe + lgkmcnt order the RAW.

        // ---- O += P V ----
#pragma unroll
        for (int ks = 0; ks < 2; ++ks) {
            const bf16x8 pa = *(const bf16x8*)&Plds[wave][m16][ks * 32 + quad * 8];
#pragma unroll
            for (int nt = 0; nt < 8; ++nt) {
                const int d = nt * 16 + m16;
                const bf16x8 vf =
                    *(const bf16x8*)&Vlds[d][((ks * 4 + quad) ^ ((d >> 3) & 7)) << 3];
                o_acc[nt] = __builtin_amdgcn_mfma_f32_16x16x32_bf16(pa, vf, o_acc[nt], 0, 0, 0);
            }
        }
    }

    // ---- epilogue ----
    float inv[4];
#pragma unroll
    for (int r = 0; r < 4; ++r) inv[r] = 1.0f / l_st[r];
#pragma unroll
    for (int nt = 0; nt < 8; ++nt)
#pragma unroll
        for (int r = 0; r < 4; ++r)
            Oh[(qrow_base + quad * 4 + r) * D_DIM + nt * 16 + m16] = o_acc[nt][r] * inv[r];
}

extern "C" void kernel_launch(void* const* d_in, const int* in_sizes, int n_in,
                              void* d_out, int out_size, void* d_ws, size_t ws_size,
                              hipStream_t stream) {
    const float* Q = (const float*)d_in[0];
    const float* K = (const float*)d_in[1];
    const float* V = (const float*)d_in[2];
    float* O = (float*)d_out;
    dim3 grid(BH * (S_LEN / BM));  // 512 blocks -> 2 blocks/CU, 16 waves/CU
    fa_fwd_kernel<<<grid, 512, 0, stream>>>(Q, K, V, O);
}

// Round 5
// 307.383 us; speedup vs baseline: 1.3837x; 1.3837x over previous
//
#include <hip/hip_runtime.h>
#include <hip/hip_bf16.h>

typedef __bf16 bf16x8 __attribute__((ext_vector_type(8)));
typedef float f32x4 __attribute__((ext_vector_type(4)));

// Problem constants
#define S_LEN 2048
#define D_DIM 128
#define BH 32            // B*H
#define BM 128           // q rows per block
#define BN 64            // keys per k-tile
#define NT (S_LEN / BN)  // 32 k-tiles
#define NWAVE 8          // 512 threads; each wave owns 16 q rows
// 1/sqrt(128) * log2(e): scores pre-multiplied, exp() becomes raw v_exp_f32 (exp2)
#define QSCALE (0.08838834764831845f * 1.4426950408889634f)

// Pack two float4s (8 floats) into one bf16x8 — by value, no address-taking.
// NB: macro parameter must NOT be named w/x/y/z (member-access tokens get substituted).
#define PACK8(dst, a, b)                                                        \
    do {                                                                        \
        dst[0] = (__bf16)(a).x; dst[1] = (__bf16)(a).y;                         \
        dst[2] = (__bf16)(a).z; dst[3] = (__bf16)(a).w;                         \
        dst[4] = (__bf16)(b).x; dst[5] = (__bf16)(b).y;                         \
        dst[6] = (__bf16)(b).z; dst[7] = (__bf16)(b).w;                         \
    } while (0)

// Pack one (lo,hi) float pair to u32 of two bf16 and store to Vlds col-swizzled.
#define VSTORE(f0, f1, jcomp)                                                   \
    do {                                                                        \
        const int d = c4 * 4 + (jcomp);                                         \
        union { __bf16 h[2]; unsigned int u; } pk;                              \
        pk.h[0] = (__bf16)(f0); pk.h[1] = (__bf16)(f1);                         \
        *(unsigned int*)&Vlds[d][((kb ^ ((d >> 3) & 7)) << 3) + jj] = pk.u;     \
    } while (0)

__global__ __launch_bounds__(512, 4)  // cap VGPR<=128: 2 blocks/CU, 16 waves
void fa_fwd_kernel(const float* __restrict__ Qg, const float* __restrict__ Kg,
                   const float* __restrict__ Vg, float* __restrict__ Og) {
    // K: [k][d] (+8 pad). V: transposed [d][k], col-block swizzle
    //   element(k,d) at col ((k>>3) ^ ((d>>3)&7))*8 + (k&7): 2-way write banks, 16B reads.
    // P: per-wave scratch (wave-local round-trip, no barrier needed).
    __shared__ __bf16 Klds[BN][D_DIM + 8];        // 17408 B
    __shared__ __bf16 Vlds[D_DIM][BN + 8];        // 18432 B
    __shared__ __bf16 Plds[NWAVE][16][BN + 8];    // 18432 B   (total 54272)

    const int bh   = blockIdx.x & (BH - 1);   // head-minor: same head -> same XCD
    const int qt   = blockIdx.x >> 5;
    const int tid  = threadIdx.x;
    const int wave = tid >> 6;
    const int lane = tid & 63;
    const int quad = lane >> 4;
    const int m16  = lane & 15;

    const float* Qh = Qg + bh * (S_LEN * D_DIM);
    const float* Kh = Kg + bh * (S_LEN * D_DIM);
    const float* Vh = Vg + bh * (S_LEN * D_DIM);
    float*       Oh = Og + bh * (S_LEN * D_DIM);

    const int qrow_base = qt * BM + wave * 16;

    // K-staging coords: thread covers chunks tid and tid+512 (8 floats each)
    const int kr0 = tid >> 4,         kc0 = (tid & 15) * 8;
    const int kr1 = (tid + 512) >> 4, kc1 = ((tid + 512) & 15) * 8;
    // V-staging coords: rows vrA..vrA+1 and vrB..vrB+1, d-chunk c4
    const int c4 = tid & 31, rp = tid >> 5;
    const int vrA = rp * 2, vrB = (rp + 16) * 2;

    // ---- Q fragments (A-layout: A[m=lane&15][k=quad*8+j]), scale*log2e folded ----
    bf16x8 qf[4];
#pragma unroll
    for (int ks = 0; ks < 4; ++ks) {
        const float* qp = Qh + (qrow_base + m16) * D_DIM + ks * 32 + quad * 8;
        const float4 a = *(const float4*)(qp);
        const float4 b = *(const float4*)(qp + 4);
        bf16x8 f;
        f[0] = (__bf16)(a.x * QSCALE); f[1] = (__bf16)(a.y * QSCALE);
        f[2] = (__bf16)(a.z * QSCALE); f[3] = (__bf16)(a.w * QSCALE);
        f[4] = (__bf16)(b.x * QSCALE); f[5] = (__bf16)(b.y * QSCALE);
        f[6] = (__bf16)(b.z * QSCALE); f[7] = (__bf16)(b.w * QSCALE);
        qf[ks] = f;
    }

    f32x4 o_acc[8];
#pragma unroll
    for (int nt = 0; nt < 8; ++nt) {
        o_acc[nt][0] = 0.f; o_acc[nt][1] = 0.f; o_acc[nt][2] = 0.f; o_acc[nt][3] = 0.f;
    }
    float m_st[4], l_st[4];
#pragma unroll
    for (int r = 0; r < 4; ++r) { m_st[r] = -1e30f; l_st[r] = 0.f; }

    // ---- prefetch registers: EIGHT NAMED float4s (no arrays -> no scratch) ----
    float4 pk0a, pk0b, pk1a, pk1b, pv0a, pv0b, pv1a, pv1b;
    {
        const float* kg = Kh;  // kt = 0
        pk0a = *(const float4*)(kg + kr0 * D_DIM + kc0);
        pk0b = *(const float4*)(kg + kr0 * D_DIM + kc0 + 4);
        pk1a = *(const float4*)(kg + kr1 * D_DIM + kc1);
        pk1b = *(const float4*)(kg + kr1 * D_DIM + kc1 + 4);
        const float* vg = Vh;
        pv0a = *(const float4*)(vg + vrA * D_DIM + c4 * 4);
        pv0b = *(const float4*)(vg + (vrA + 1) * D_DIM + c4 * 4);
        pv1a = *(const float4*)(vg + vrB * D_DIM + c4 * 4);
        pv1b = *(const float4*)(vg + (vrB + 1) * D_DIM + c4 * 4);
    }

    for (int kt = 0; kt < NT; ++kt) {
        __syncthreads();  // all waves done reading LDS tiles of kt-1

        // ---- convert prefetched regs -> LDS ----
        {
            bf16x8 wreg;
            PACK8(wreg, pk0a, pk0b);
            *(bf16x8*)&Klds[kr0][kc0] = wreg;
            PACK8(wreg, pk1a, pk1b);
            *(bf16x8*)&Klds[kr1][kc1] = wreg;
        }
        {
            int kb = vrA >> 3, jj = vrA & 7;
            VSTORE(pv0a.x, pv0b.x, 0); VSTORE(pv0a.y, pv0b.y, 1);
            VSTORE(pv0a.z, pv0b.z, 2); VSTORE(pv0a.w, pv0b.w, 3);
            kb = vrB >> 3; jj = vrB & 7;
            VSTORE(pv1a.x, pv1b.x, 0); VSTORE(pv1a.y, pv1b.y, 1);
            VSTORE(pv1a.z, pv1b.z, 2); VSTORE(pv1a.w, pv1b.w, 3);
        }

        // ---- issue next tile's loads now; latency hides under compute ----
        if (kt + 1 < NT) {
            const float* kg = Kh + (kt + 1) * BN * D_DIM;
            pk0a = *(const float4*)(kg + kr0 * D_DIM + kc0);
            pk0b = *(const float4*)(kg + kr0 * D_DIM + kc0 + 4);
            pk1a = *(const float4*)(kg + kr1 * D_DIM + kc1);
            pk1b = *(const float4*)(kg + kr1 * D_DIM + kc1 + 4);
            const float* vg = Vh + (kt + 1) * BN * D_DIM;
            pv0a = *(const float4*)(vg + vrA * D_DIM + c4 * 4);
            pv0b = *(const float4*)(vg + (vrA + 1) * D_DIM + c4 * 4);
            pv1a = *(const float4*)(vg + vrB * D_DIM + c4 * 4);
            pv1b = *(const float4*)(vg + (vrB + 1) * D_DIM + c4 * 4);
        }

        __syncthreads();  // LDS tiles ready

        // ---- S = (Q*scale*log2e) K^T ----
        f32x4 sacc[4];
#pragma unroll
        for (int nt = 0; nt < 4; ++nt) {
            sacc[nt][0] = 0.f; sacc[nt][1] = 0.f; sacc[nt][2] = 0.f; sacc[nt][3] = 0.f;
        }
#pragma unroll
        for (int ks = 0; ks < 4; ++ks)
#pragma unroll
            for (int nt = 0; nt < 4; ++nt) {
                const bf16x8 kf = *(const bf16x8*)&Klds[nt * 16 + m16][ks * 32 + quad * 8];
                sacc[nt] = __builtin_amdgcn_mfma_f32_16x16x32_bf16(qf[ks], kf, sacc[nt], 0, 0, 0);
            }

        // ---- online softmax, exp2 domain (C-rows: quad*4+r) ----
        {
            float mx[4];
#pragma unroll
            for (int r = 0; r < 4; ++r)
                mx[r] = fmaxf(fmaxf(sacc[0][r], sacc[1][r]), fmaxf(sacc[2][r], sacc[3][r]));
#pragma unroll
            for (int xm = 1; xm <= 8; xm <<= 1)
#pragma unroll
                for (int r = 0; r < 4; ++r)
                    mx[r] = fmaxf(mx[r], __shfl_xor(mx[r], xm, 64));
            float alpha[4], rs[4];
#pragma unroll
            for (int r = 0; r < 4; ++r) {
                const float mnew = fmaxf(m_st[r], mx[r]);
                alpha[r] = __builtin_amdgcn_exp2f(m_st[r] - mnew);
                m_st[r] = mnew;
                rs[r] = 0.f;
            }
#pragma unroll
            for (int nt = 0; nt < 4; ++nt) {
#pragma unroll
                for (int r = 0; r < 4; ++r) {
                    const float p = __builtin_amdgcn_exp2f(sacc[nt][r] - m_st[r]);
                    rs[r] += p;
                    Plds[wave][quad * 4 + r][nt * 16 + m16] = (__bf16)p;
                }
            }
#pragma unroll
            for (int xm = 1; xm <= 8; xm <<= 1)
#pragma unroll
                for (int r = 0; r < 4; ++r)
                    rs[r] += __shfl_xor(rs[r], xm, 64);
#pragma unroll
            for (int r = 0; r < 4; ++r)
                l_st[r] = l_st[r] * alpha[r] + rs[r];
#pragma unroll
            for (int nt = 0; nt < 8; ++nt)
#pragma unroll
                for (int r = 0; r < 4; ++r)
                    o_acc[nt][r] *= alpha[r];
        }
        // NO barrier: Plds[wave] is wave-local; DS pipe + lgkmcnt order the RAW.

        // ---- O += P V ----
#pragma unroll
        for (int ks = 0; ks < 2; ++ks) {
            const bf16x8 pa = *(const bf16x8*)&Plds[wave][m16][ks * 32 + quad * 8];
#pragma unroll
            for (int nt = 0; nt < 8; ++nt) {
                const int d = nt * 16 + m16;
                const bf16x8 vf =
                    *(const bf16x8*)&Vlds[d][((ks * 4 + quad) ^ ((d >> 3) & 7)) << 3];
                o_acc[nt] = __builtin_amdgcn_mfma_f32_16x16x32_bf16(pa, vf, o_acc[nt], 0, 0, 0);
            }
        }
    }

    // ---- epilogue ----
    float inv[4];
#pragma unroll
    for (int r = 0; r < 4; ++r) inv[r] = 1.0f / l_st[r];
#pragma unroll
    for (int nt = 0; nt < 8; ++nt)
#pragma unroll
        for (int r = 0; r < 4; ++r)
            Oh[(qrow_base + quad * 4 + r) * D_DIM + nt * 16 + m16] = o_acc[nt][r] * inv[r];
}

extern "C" void kernel_launch(void* const* d_in, const int* in_sizes, int n_in,
                              void* d_out, int out_size, void* d_ws, size_t ws_size,
                              hipStream_t stream) {
    const float* Q = (const float*)d_in[0];
    const float* K = (const float*)d_in[1];
    const float* V = (const float*)d_in[2];
    float* O = (float*)d_out;
    dim3 grid(BH * (S_LEN / BM));  // 512 blocks -> 2 blocks/CU, 16 waves/CU
    fa_fwd_kernel<<<grid, 512, 0, stream>>>(Q, K, V, O);
}